// Round 1
// baseline (328.482 us; speedup 1.0000x reference)
//
#include <hip/hip_runtime.h>
#include <hip/hip_bf16.h>
#include <stdint.h>

// Problem constants
#define BT    (256*2048)      // 524288 tokens
#define DIN   25
#define DP    128
#define MTILE 128             // tokens per block
#define NBLK  (BT/MTILE)      // 4096 blocks
#define HSTR  136             // h row stride in bf16 elems (pad 128->136: conflict-free frag reads)

typedef __attribute__((ext_vector_type(8))) __bf16          bf16x8;
typedef __attribute__((ext_vector_type(8))) unsigned short  u16x8;
typedef __attribute__((ext_vector_type(4))) float           f32x4;

// smem layout (bytes). h-region is unioned with the x staging tile (x dead after LN).
#define SM_H     0                         // h: 128*136*2 = 34816 ; x-stage: 128*25*4 = 12800
#define SM_XN    34816                     // xn A-frags: 8 frags * 1024B = 8192
#define SM_SMALL (34816 + 8192)            // gamma(25f) beta(25f) b1(128f) b2(128f) = 306 floats
#define SM_BYTES (SM_SMALL + 306*4)        // 44232 B -> 3 blocks/CU

__device__ __forceinline__ unsigned short f2bf(float f) {
  unsigned int u = __float_as_uint(f);
  u += 0x7fffu + ((u >> 16) & 1u);          // round-to-nearest-even
  return (unsigned short)(u >> 16);
}

// exact-erf GELU via Abramowitz&Stegun 7.1.26 (|eps|<=1.5e-7), ~15 VALU ops
__device__ __forceinline__ float gelu_exact(float x) {
  float z  = 0.70710678118654752f * x;
  float az = __builtin_fabsf(z);
  float t  = __builtin_amdgcn_rcpf(1.0f + 0.3275911f * az);
  float p  = t*(0.254829592f + t*(-0.284496736f + t*(1.421413741f +
             t*(-1.453152027f + t*1.061405429f))));
  float e  = __expf(-z*z);                  // v_exp_f32 path
  float erf_az = 1.0f - p*e;
  float erf_z  = (x < 0.f) ? -erf_az : erf_az;
  return 0.5f * x * (1.0f + erf_z);
}

__device__ __forceinline__ void async16(void* lds, const void* g) {
  __builtin_amdgcn_global_load_lds(
      (const __attribute__((address_space(1))) unsigned int*)g,
      (__attribute__((address_space(3)))       unsigned int*)lds, 16, 0, 0);
}

// ---------------------------------------------------------------------------
// Prep: pack w1 (K padded 25->32, zero fill) and w2 into bf16 MFMA B-fragment
// lane order. B-frag (16x16x32): elem(lane,j) = B[k = (lane>>4)*8 + j][n = nt*16 + (lane&15)]
// ws layout: [w1 frags nt=0..7][w2 frags f = nt*4 + ks, ks = K/32 step]  (each frag 512 bf16)
// ---------------------------------------------------------------------------
__global__ void prep_kernel(const float* __restrict__ w1, const float* __restrict__ w2,
                            unsigned short* __restrict__ wf) {
  int idx = blockIdx.x * 256 + threadIdx.x;
  if (idx >= 40 * 512) return;
  int f = idx >> 9, r = idx & 511, l = r >> 3, j = r & 7;
  float val;
  if (f < 8) {                       // w1 frag, nt = f
    int k = (l >> 4) * 8 + j;
    int n = f * 16 + (l & 15);
    val = (k < DIN) ? w1[k * DP + n] : 0.f;
  } else {                           // w2 frag
    int g = f - 8, nt = g >> 2, ks = g & 3;
    int k = ks * 32 + (l >> 4) * 8 + j;
    int n = nt * 16 + (l & 15);
    val = w2[k * DP + n];
  }
  wf[idx] = f2bf(val);
}

// ---------------------------------------------------------------------------
// Fused LN -> mm1(+b1,GELU) -> mm2(+b2). One 128-token tile per block.
// ---------------------------------------------------------------------------
__global__ __launch_bounds__(256, 2) void fused_kernel(
    const float* __restrict__ x,   const float* __restrict__ gam,
    const float* __restrict__ bet, const float* __restrict__ b1,
    const float* __restrict__ b2,  const unsigned short* __restrict__ wfr,
    float* __restrict__ out) {
  __shared__ __align__(16) unsigned char smem[SM_BYTES];
  const int tid  = threadIdx.x;
  const int lane = tid & 63, w = tid >> 6;
  const int quad = lane >> 4, l15 = lane & 15;
  const long long row0 = (long long)blockIdx.x * MTILE;

  // ---- stage x tile (3200 floats = 800 x 16B) direct to LDS ----
  {
    const float* src = x + row0 * DIN;
    for (int c = tid; c < 800; c += 256)
      async16(smem + c * 16, src + c * 4);
  }
  // ---- stage small vectors ----
  float* sg  = (float*)(smem + SM_SMALL);
  float* sbt = sg + 25;
  float* sb1 = sbt + 25;
  float* sb2 = sb1 + 128;
  if (tid < 128) { sb1[tid] = b1[tid]; sb2[tid] = b2[tid]; }
  if (tid < 25)  { sg[tid] = gam[tid]; sbt[tid] = bet[tid]; }
  __syncthreads();   // drains global_load_lds (vmcnt) + LDS writes

  // ---- LayerNorm: one thread per token; emit xn bf16 in A-frag lane order ----
  if (tid < MTILE) {
    const float* xr = (const float*)smem + tid * DIN;
    float s = 0.f;
#pragma unroll
    for (int j = 0; j < DIN; j++) s += xr[j];
    float mu = s * (1.f / DIN);
    float v = 0.f;
#pragma unroll
    for (int j = 0; j < DIN; j++) { float d = xr[j] - mu; v += d * d; }
    float inv = rsqrtf(v * (1.f / DIN) + 1e-5f);
    int mt = tid >> 4, mr = tid & 15;
    unsigned char* fb = smem + SM_XN + mt * 1024;
#pragma unroll
    for (int q = 0; q < 4; q++) {
      u16x8 pk;
#pragma unroll
      for (int j = 0; j < 8; j++) {
        int k = q * 8 + j;
        float val = (k < DIN) ? ((xr[k] - mu) * inv * sg[k] + sbt[k]) : 0.f;
        pk[j] = f2bf(val);
      }
      *(u16x8*)(fb + (mr + 16 * q) * 16) = pk;   // conflict-free ds_write_b128
    }
  }
  __syncthreads();   // xn ready; x-stage region now dead -> reusable as h

  // ---- mm1: h = gelu(xn @ w1 + b1), wave w does row-tiles {2w, 2w+1} ----
  const unsigned char* wfb = (const unsigned char*)wfr;
  bf16x8 wb1[8];
#pragma unroll
  for (int nt = 0; nt < 8; nt++)
    wb1[nt] = *(const bf16x8*)(wfb + nt * 1024 + lane * 16);

  unsigned short* hb = (unsigned short*)smem;
  const f32x4 zf = {0.f, 0.f, 0.f, 0.f};
#pragma unroll
  for (int mi = 0; mi < 2; mi++) {
    int mt = w * 2 + mi;
    bf16x8 a = *(const bf16x8*)(smem + SM_XN + mt * 1024 + lane * 16);
    f32x4 acc[8];
#pragma unroll
    for (int nt = 0; nt < 8; nt++)
      acc[nt] = __builtin_amdgcn_mfma_f32_16x16x32_bf16(a, wb1[nt], zf, 0, 0, 0);
    // epilogue: bias + exact gelu -> h (bf16, row-major stride HSTR)
#pragma unroll
    for (int nt = 0; nt < 8; nt++) {
      float bias = sb1[nt * 16 + l15];
      int col = nt * 16 + l15;
#pragma unroll
      for (int r = 0; r < 4; r++) {
        int row = mt * 16 + quad * 4 + r;
        float hp = acc[nt][r] + bias;
        hb[row * HSTR + col] = f2bf(gelu_exact(hp));
      }
    }
  }
  __syncthreads();   // h ready

  // ---- mm2: out = h @ w2 + b2. Wave w owns col-tiles {2w,2w+1}; w2 frags in regs ----
  bf16x8 wb2[2][4];
#pragma unroll
  for (int ni = 0; ni < 2; ni++)
#pragma unroll
    for (int ks = 0; ks < 4; ks++)
      wb2[ni][ks] = *(const bf16x8*)(wfb + 8192 + (((w * 2 + ni) * 4) + ks) * 1024 + lane * 16);

  float bias0 = sb2[(w * 2 + 0) * 16 + l15];
  float bias1 = sb2[(w * 2 + 1) * 16 + l15];

  for (int mt = 0; mt < 8; mt++) {
    f32x4 a0 = zf, a1 = zf;
    f32x4 acc0 = zf, acc1 = zf;
#pragma unroll
    for (int ks = 0; ks < 4; ks++) {
      bf16x8 af = *(const bf16x8*)(smem + (mt * 16 + l15) * (HSTR * 2) + ks * 64 + quad * 16);
      acc0 = __builtin_amdgcn_mfma_f32_16x16x32_bf16(af, wb2[0][ks], acc0, 0, 0, 0);
      acc1 = __builtin_amdgcn_mfma_f32_16x16x32_bf16(af, wb2[1][ks], acc1, 0, 0, 0);
    }
    float* orow = out + (row0 + mt * 16) * DP;
    int c0 = (w * 2 + 0) * 16 + l15;
    int c1 = (w * 2 + 1) * 16 + l15;
#pragma unroll
    for (int r = 0; r < 4; r++) {
      int row = quad * 4 + r;
      orow[row * DP + c0] = acc0[r] + bias0;
      orow[row * DP + c1] = acc1[r] + bias1;
    }
    (void)a0; (void)a1;
  }
}

extern "C" void kernel_launch(void* const* d_in, const int* in_sizes, int n_in,
                              void* d_out, int out_size, void* d_ws, size_t ws_size,
                              hipStream_t stream) {
  const float* x   = (const float*)d_in[0];
  const float* gam = (const float*)d_in[1];
  const float* bet = (const float*)d_in[2];
  const float* w1  = (const float*)d_in[3];
  const float* b1  = (const float*)d_in[4];
  const float* w2  = (const float*)d_in[5];
  const float* b2  = (const float*)d_in[6];
  float* out = (float*)d_out;
  unsigned short* wf = (unsigned short*)d_ws;   // 40KB of packed bf16 weight frags

  prep_kernel<<<80, 256, 0, stream>>>(w1, w2, wf);
  fused_kernel<<<NBLK, 256, 0, stream>>>(x, gam, bet, b1, b2, wf, out);
}